// Round 4
// baseline (282.653 us; speedup 1.0000x reference)
//
#include <hip/hip_runtime.h>
#include <hip/hip_bf16.h>
#include <stdint.h>

#define B_ 8
#define N_ 2048
#define F_ 64
#define FH_ 64
#define H_ 4
#define C_ (H_*FH_)
#define CHUNK 64
#define NCHUNK (N_/CHUNK)
#define LOG2E 1.44269504088896340736f

typedef short short8 __attribute__((ext_vector_type(8)));   // 8 bf16 raw bits (4 VGPRs)
typedef float f32x4 __attribute__((ext_vector_type(4)));

// float -> bf16 raw bits (RNE)
__device__ __forceinline__ short f2bf(float f) {
    __hip_bfloat16 h = __float2bfloat16(f);
    return __builtin_bit_cast(short, h);
}

// ---------------- KF: fused [k1 feats+scores | kp mask-pack] ----------------
// Blocks [0,1024): k1 (featsT + ss/sn, W transposed in-LDS -- k0 eliminated).
// Blocks [1024,5120): kp (A -> 1-bit mask). The two parts are independent; fusing
// them lets the ~19 us HBM-bound A read overlap the k1 MFMA work.
// (R2 profile: fills hit 6.9 TB/s on this box; A-read floor ~19 us.)
__global__ __launch_bounds__(256) void kf(const float* __restrict__ A,
                                          const float* __restrict__ X,
                                          const float* __restrict__ W,
                                          const float* __restrict__ a_self,
                                          const float* __restrict__ a_neigh,
                                          unsigned long long* __restrict__ Amask,
                                          __hip_bfloat16* __restrict__ featsT,
                                          float* __restrict__ ss,
                                          float* __restrict__ sn) {
    __shared__ float a_lds[2][FH_];
    __shared__ __hip_bfloat16 cw_lds[FH_ * 72];    // W^T (bf16) during MFMA, then C
    const int bx = blockIdx.x;
    const int tid = threadIdx.x;
    const int wave = tid >> 6, lane = tid & 63;

    if (bx >= 1024) {
        // ---------------- kp part ----------------
        const int R = (bx - 1024) * 4 + wave;      // global row 0..16383 (= b*N + i)
        const float* arow = A + (size_t)R * N_;
        unsigned long long* mrow = Amask + (size_t)R * (N_ / 64);
#pragma unroll
        for (int i = 0; i < 8; ++i) {              // 8 x 256 cols
            float a0 = arow[i * 256 + lane];
            float a1 = arow[i * 256 + 64 + lane];
            float a2 = arow[i * 256 + 128 + lane];
            float a3 = arow[i * 256 + 192 + lane];
            unsigned long long m0 = __ballot(a0 != 0.0f);
            unsigned long long m1 = __ballot(a1 != 0.0f);
            unsigned long long m2 = __ballot(a2 != 0.0f);
            unsigned long long m3 = __ballot(a3 != 0.0f);
            if (lane == 0) {
                mrow[i * 4 + 0] = m0; mrow[i * 4 + 1] = m1;
                mrow[i * 4 + 2] = m2; mrow[i * 4 + 3] = m3;
            }
        }
        return;
    }

    // ---------------- k1 part ----------------
    const int nb = bx & 31, h = (bx >> 5) & 3, b = bx >> 7;

    if (tid < 64)       a_lds[0][tid] = a_self[h * FH_ + tid];
    else if (tid < 128) a_lds[1][tid - 64] = a_neigh[h * FH_ + tid - 64];
    {   // stage W[h] transposed to bf16: cw_lds[o*72+f] = bf16(W[h][f][o])
        int f = tid >> 2, o0 = (tid & 3) * 16;
        const float* wsrc = W + ((size_t)(h * F_ + f)) * FH_ + o0;
#pragma unroll
        for (int k = 0; k < 16; ++k)
            cw_lds[(o0 + k) * 72 + f] = __float2bfloat16(wsrc[k]);
    }
    __syncthreads();

    const int m = lane & 15, q = lane >> 4;
    const int nl = wave * 16 + m;               // local column 0..63
    const int n = nb * 64 + nl;                 // B-frag column (node index)
    f32x4 acc[4] = {};
#pragma unroll
    for (int ks = 0; ks < 2; ++ks) {            // K = F = 64, two steps of 32
        const float* xp = X + ((size_t)(b * N_ + n)) * F_ + ks * 32 + q * 8;
        float4 x0 = *(const float4*)xp;
        float4 x1 = *(const float4*)(xp + 4);
        short8 bfrag;
        bfrag[0] = f2bf(x0.x); bfrag[1] = f2bf(x0.y);
        bfrag[2] = f2bf(x0.z); bfrag[3] = f2bf(x0.w);
        bfrag[4] = f2bf(x1.x); bfrag[5] = f2bf(x1.y);
        bfrag[6] = f2bf(x1.z); bfrag[7] = f2bf(x1.w);
#pragma unroll
        for (int ot = 0; ot < 4; ++ot) {
            short8 afrag = *(const short8*)(cw_lds + (ot * 16 + m) * 72 + ks * 32 + q * 8);
            acc[ot] = __builtin_amdgcn_mfma_f32_16x16x32_bf16(afrag, bfrag, acc[ot], 0, 0, 0);
        }
    }
    __syncthreads();    // all W reads done before C overwrites the buffer
    float ssv = 0.f, snv = 0.f;
#pragma unroll
    for (int ot = 0; ot < 4; ++ot) {
#pragma unroll
        for (int r = 0; r < 4; ++r) {
            int orow = ot * 16 + q * 4 + r;     // C: row=(lane>>4)*4+r, col=lane&15
            float v = acc[ot][r];
            cw_lds[orow * 72 + nl] = __float2bfloat16(v);
            ssv += v * a_lds[0][orow];
            snv += v * a_lds[1][orow];
        }
    }
    ssv += __shfl_xor(ssv, 16); ssv += __shfl_xor(ssv, 32);
    snv += __shfl_xor(snv, 16); snv += __shfl_xor(snv, 32);
    __syncthreads();
    {   // coalesced featsT store: thread t -> feature o = t>>2, 16-col chunk (t&3)
        int o = tid >> 2, c = (tid & 3) * 16;
        const __hip_bfloat16* src = cw_lds + o * 72 + c;
        __hip_bfloat16* dst = featsT + ((size_t)(b * H_ + h) * FH_ + o) * N_ + nb * 64 + c;
        *(uint4*)dst       = *(const uint4*)src;
        *(uint4*)(dst + 8) = *(const uint4*)(src + 8);
    }
    if (lane < 16) {
        size_t idx = ((size_t)(b * H_ + h)) * N_ + n;
        ss[idx] = ssv * LOG2E;
        sn[idx] = snv * LOG2E;
    }
}

// ---------------- K3: register-direct fused softmax+PV (R16) ----------------
// R3 post-mortem: k3 was throughput-bound on the fv LDS ROUND-TRIP (DMA 256 MB +
// 4x wave re-read = 160 KB LDS/chunk/CU) stacked with VALU P-build; barriers
// serialized the pipes. Restructure: B-fragments are directly loadable from
// global featsT (lane(m,q): 16B contiguous at featsT[o][cb+q*8]; q=0..3 of same
// m cover one 64B line). fv LDS, DMA, double-buffer, and ALL in-loop barriers
// deleted. Each wave owns 32 rows (2 row-groups sharing B-frags in registers)
// -> fv global traffic halves to 512 MB, L2-resident. Loads issue at iteration
// top; the ~400-cycle load-independent P-build hides L2 latency before MFMAs.
// Masks prefetched 1 chunk ahead. Numerics bit-identical to R12.
__global__ __launch_bounds__(256) void k3_attn(const unsigned int* __restrict__ Amask,
                                               const __hip_bfloat16* __restrict__ featsT,
                                               const float* __restrict__ ss,
                                               const float* __restrict__ sn,
                                               const float* __restrict__ bias,
                                               float* __restrict__ out) {
    __shared__ float e1_lds[N_];                       // 8 KB: 2^sn_j
    __shared__ float e2_lds[N_];                       // 8 KB: 2^(0.2 sn_j)

    const int tile = blockIdx.x, h = blockIdx.y, b = blockIdx.z;   // tile in [0,16)
    const int tid = threadIdx.x, wave = tid >> 6, lane = tid & 63;
    const int m = lane & 15, q = lane >> 4;
    const int wavebase = tile * 128 + wave * 32;       // first of this wave's 32 rows

    {   // e-tables: 512 float4 slots, 2 per thread
        const float4* snrow = (const float4*)(sn + ((size_t)(b * H_ + h)) * N_);
        float4* e1v = (float4*)e1_lds;
        float4* e2v = (float4*)e2_lds;
#pragma unroll
        for (int i = 0; i < 2; ++i) {
            int idx = tid + i * 256;
            float4 v = snrow[idx];
            float4 u1, u2;
            u1.x = exp2f(v.x); u1.y = exp2f(v.y); u1.z = exp2f(v.z); u1.w = exp2f(v.w);
            u2.x = exp2f(0.2f * v.x); u2.y = exp2f(0.2f * v.y);
            u2.z = exp2f(0.2f * v.z); u2.w = exp2f(0.2f * v.w);
            e1v[idx] = u1; e2v[idx] = u2;
        }
    }
    // per-row self terms for the two 16-row groups (A-frag row = lane&15)
    const float* ssrow = ss + ((size_t)(b * H_ + h)) * N_;
    const float ssi0 = ssrow[wavebase + m];
    const float ssi1 = ssrow[wavebase + 16 + m];
    const float e1i0 = exp2f(ssi0), e2i0 = exp2f(0.2f * ssi0);
    const float e1i1 = exp2f(ssi1), e2i1 = exp2f(0.2f * ssi1);

    const __hip_bfloat16* fhead = featsT + ((size_t)(b * H_ + h)) * FH_ * N_;
    const unsigned int* mrow0 = Amask + ((size_t)(b * N_) + wavebase + m) * (N_ / 32);
    const unsigned int* mrow1 = mrow0 + (size_t)16 * (N_ / 32);

    __syncthreads();    // e-tables ready; no barriers after this point

    f32x4 acc[2][4] = {};       // [group][ct] -- fully unrolled, static indices
    f32x4 accl[2] = {};         // [group] row-sum accumulators
    short8 ones;
#pragma unroll
    for (int s = 0; s < 8; ++s) ones[s] = (short)0x3F80;   // bf16 1.0

    uint2 mk0 = *(const uint2*)(mrow0);     // masks for chunk 0
    uint2 mk1 = *(const uint2*)(mrow1);

    for (int c = 0; c < NCHUNK; ++c) {
        const int cg = c * CHUNK;
        // fv B-fragments straight from global (L2-resident featsT panel):
        // lane(m,q), feature o=ct*16+m, k-cols cg+q*8 (chain A) / +32 (chain B)
        short8 fA[4], fB[4];
#pragma unroll
        for (int ct = 0; ct < 4; ++ct) {
            const __hip_bfloat16* fp = fhead + (size_t)(ct * 16 + m) * N_ + cg + q * 8;
            fA[ct] = *(const short8*)fp;
            fB[ct] = *(const short8*)(fp + 32);
        }
        // mask prefetch for next chunk (keeps mask latency off the P-build path)
        uint2 mk0n = mk0, mk1n = mk1;
        if (c + 1 < NCHUNK) {
            mk0n = *(const uint2*)(mrow0 + (c + 1) * 2);
            mk1n = *(const uint2*)(mrow1 + (c + 1) * 2);
        }

        // e-tables (broadcast within q-group -> near-free LDS reads)
        float4 eA10 = *(const float4*)(e1_lds + cg + q * 8);
        float4 eA11 = *(const float4*)(e1_lds + cg + q * 8 + 4);
        float4 eB10 = *(const float4*)(e1_lds + cg + 32 + q * 8);
        float4 eB11 = *(const float4*)(e1_lds + cg + 32 + q * 8 + 4);
        float4 eA20 = *(const float4*)(e2_lds + cg + q * 8);
        float4 eA21 = *(const float4*)(e2_lds + cg + q * 8 + 4);
        float4 eB20 = *(const float4*)(e2_lds + cg + 32 + q * 8);
        float4 eB21 = *(const float4*)(e2_lds + cg + 32 + q * 8 + 4);
        float e1A[8] = {eA10.x, eA10.y, eA10.z, eA10.w, eA11.x, eA11.y, eA11.z, eA11.w};
        float e1B[8] = {eB10.x, eB10.y, eB10.z, eB10.w, eB11.x, eB11.y, eB11.z, eB11.w};
        float e2A[8] = {eA20.x, eA20.y, eA20.z, eA20.w, eA21.x, eA21.y, eA21.z, eA21.w};
        float e2B[8] = {eB20.x, eB20.y, eB20.z, eB20.w, eB21.x, eB21.y, eB21.z, eB21.w};

        // P for both row-groups (load-independent: hides the fv L2 latency)
        short8 p0A, p0B, p1A, p1B;
#pragma unroll
        for (int s = 0; s < 8; ++s) {
            // exp2(leaky(si+sj)) = max(e1i*e1j, e2i*e2j); adjacency via bit test
            float vA0 = fmaxf(e1i0 * e1A[s], e2i0 * e2A[s]);
            float vB0 = fmaxf(e1i0 * e1B[s], e2i0 * e2B[s]);
            float vA1 = fmaxf(e1i1 * e1A[s], e2i1 * e2A[s]);
            float vB1 = fmaxf(e1i1 * e1B[s], e2i1 * e2B[s]);
            const int bit = q * 8 + s;
            p0A[s] = (mk0.x >> bit) & 1 ? f2bf(vA0) : (short)0;
            p0B[s] = (mk0.y >> bit) & 1 ? f2bf(vB0) : (short)0;
            p1A[s] = (mk1.x >> bit) & 1 ? f2bf(vA1) : (short)0;
            p1B[s] = (mk1.y >> bit) & 1 ? f2bf(vB1) : (short)0;
        }
#pragma unroll
        for (int ct = 0; ct < 4; ++ct) {
            acc[0][ct] = __builtin_amdgcn_mfma_f32_16x16x32_bf16(p0A, fA[ct], acc[0][ct], 0, 0, 0);
            acc[0][ct] = __builtin_amdgcn_mfma_f32_16x16x32_bf16(p0B, fB[ct], acc[0][ct], 0, 0, 0);
            acc[1][ct] = __builtin_amdgcn_mfma_f32_16x16x32_bf16(p1A, fA[ct], acc[1][ct], 0, 0, 0);
            acc[1][ct] = __builtin_amdgcn_mfma_f32_16x16x32_bf16(p1B, fB[ct], acc[1][ct], 0, 0, 0);
        }
        accl[0] = __builtin_amdgcn_mfma_f32_16x16x32_bf16(p0A, ones, accl[0], 0, 0, 0);
        accl[0] = __builtin_amdgcn_mfma_f32_16x16x32_bf16(p0B, ones, accl[0], 0, 0, 0);
        accl[1] = __builtin_amdgcn_mfma_f32_16x16x32_bf16(p1A, ones, accl[1], 0, 0, 0);
        accl[1] = __builtin_amdgcn_mfma_f32_16x16x32_bf16(p1B, ones, accl[1], 0, 0, 0);

        mk0 = mk0n; mk1 = mk1n;
    }

    float bc[4];
#pragma unroll
    for (int ct = 0; ct < 4; ++ct) bc[ct] = bias[h * FH_ + ct * 16 + m];

#pragma unroll
    for (int g = 0; g < 2; ++g) {
#pragma unroll
        for (int r = 0; r < 4; ++r) {
            float inv = 1.0f / accl[g][r];      // row sum (all cols identical)
            int gr = wavebase + g * 16 + q * 4 + r;
#pragma unroll
            for (int ct = 0; ct < 4; ++ct) {
                float v = acc[g][ct][r] * inv + bc[ct];
                out[((size_t)(b * N_) + gr) * C_ + h * FH_ + ct * 16 + m] = fmaxf(v, 0.0f);
            }
        }
    }
}

extern "C" void kernel_launch(void* const* d_in, const int* in_sizes, int n_in,
                              void* d_out, int out_size, void* d_ws, size_t ws_size,
                              hipStream_t stream) {
    const float* X       = (const float*)d_in[0];
    const float* A       = (const float*)d_in[1];
    const float* W       = (const float*)d_in[2];
    const float* bias    = (const float*)d_in[3];
    const float* a_self  = (const float*)d_in[4];
    const float* a_neigh = (const float*)d_in[5];
    float* out = (float*)d_out;   // reference output dtype is float32

    char* ws = (char*)d_ws;
    __hip_bfloat16* featsT = (__hip_bfloat16*)(ws);             // 8 MB   [B][H][FH][N]
    float* ss              = (float*)(ws + 8421376);            // 256 KB [B][H][N]
    float* sn              = (float*)(ws + 8683520);            // 256 KB [B][H][N]
    unsigned long long* Am = (unsigned long long*)(ws + 8945664); // 4 MB bitmask

    kf      <<<5120, 256, 0, stream>>>(A, X, W, a_self, a_neigh, Am, featsT, ss, sn);
    k3_attn <<<dim3(N_ / 128, H_, B_), 256, 0, stream>>>((const unsigned int*)Am, featsT, ss, sn, bias, out);
}